// Round 1
// baseline (86.558 us; speedup 1.0000x reference)
//
#include <hip/hip_runtime.h>
#include <stdint.h>

// ---------------------------------------------------------------------------
// RandomParameterizedQuantumConvolutionLayer — fully fused single kernel.
// out = T(12x81)·g, g[K] = f0[mf] * g123[r], K = mf*32+r (r<27 used).
// Each block (512 threads, 8 waves) redundantly builds T (cheap: ~9k
// SIMD-cycles, hidden under HBM latency of the prefetched x tiles), then
// processes 2 tiles of 512 rows. T fragments live in LDS; d_ws is unused.
// Grid 512 = 2 blocks/CU resident (47 KB LDS each), 16 waves/CU.
// ---------------------------------------------------------------------------

namespace {

typedef _Float16 half8 __attribute__((ext_vector_type(8)));
typedef _Float16 half4 __attribute__((ext_vector_type(4)));
typedef float float4v __attribute__((ext_vector_type(4)));

struct GateList {
  int ty[45];   // 0..6 single (rx,ry,rz,s,t,p,u3); 10..19 double
  int q0[45];
  int q1[45];
  int off[45];  // param offset
};

// ---- CPython-compatible MT19937 (random.Random) ----
struct PyRandom {
  uint32_t mt[624];
  int mti;
  void init_genrand(uint32_t s) {
    mt[0] = s;
    for (int i = 1; i < 624; ++i)
      mt[i] = 1812433253u * (mt[i - 1] ^ (mt[i - 1] >> 30)) + (uint32_t)i;
    mti = 624;
  }
  void init_by_array(const uint32_t* key, int klen) {
    init_genrand(19650218u);
    int i = 1, j = 0;
    int k = 624 > klen ? 624 : klen;
    for (; k; --k) {
      mt[i] = (mt[i] ^ ((mt[i - 1] ^ (mt[i - 1] >> 30)) * 1664525u)) + key[j] + (uint32_t)j;
      ++i; ++j;
      if (i >= 624) { mt[0] = mt[623]; i = 1; }
      if (j >= klen) j = 0;
    }
    for (k = 623; k; --k) {
      mt[i] = (mt[i] ^ ((mt[i - 1] ^ (mt[i - 1] >> 30)) * 1566083941u)) - (uint32_t)i;
      ++i;
      if (i >= 624) { mt[0] = mt[623]; i = 1; }
    }
    mt[0] = 0x80000000u;
    mti = 624;
  }
  uint32_t genrand() {
    if (mti >= 624) {
      const uint32_t mag[2] = {0u, 0x9908b0dfu};
      int kk; uint32_t y;
      for (kk = 0; kk < 227; ++kk) {
        y = (mt[kk] & 0x80000000u) | (mt[kk + 1] & 0x7fffffffu);
        mt[kk] = mt[kk + 397] ^ (y >> 1) ^ mag[y & 1];
      }
      for (; kk < 623; ++kk) {
        y = (mt[kk] & 0x80000000u) | (mt[kk + 1] & 0x7fffffffu);
        mt[kk] = mt[kk - 227] ^ (y >> 1) ^ mag[y & 1];
      }
      y = (mt[623] & 0x80000000u) | (mt[0] & 0x7fffffffu);
      mt[623] = mt[396] ^ (y >> 1) ^ mag[y & 1];
      mti = 0;
    }
    uint32_t y = mt[mti++];
    y ^= y >> 11;
    y ^= (y << 7) & 0x9d2c5680u;
    y ^= (y << 15) & 0xefc60000u;
    y ^= y >> 18;
    return y;
  }
  uint32_t getrandbits(int k) { return genrand() >> (32 - k); }
  uint32_t randbelow(uint32_t n) {
    int k = 32 - __builtin_clz(n);
    uint32_t r = getrandbits(k);
    while (r >= n) r = getrandbits(k);
    return r;
  }
};

void build_gatelist(GateList& gl) {
  PyRandom rng;
  uint32_t key = 1024u;
  rng.init_by_array(&key, 1);
  static const int PC_S[7]  = {1, 1, 1, 0, 0, 1, 3};
  static const int PC_D[10] = {1, 1, 1, 0, 0, 1, 0, 3, 0, 0};
  int off = 0, idx = 0;
  for (int circ = 0; circ < 3; ++circ) {
    for (int blk = 0; blk < 3; ++blk) {
      for (int i = 0; i < 4; ++i) {
        int g = (int)rng.randbelow(7);            // choice(SINGLE)
        gl.ty[idx] = g; gl.q0[idx] = i; gl.q1[idx] = 0; gl.off[idx] = off;
        off += PC_S[g]; ++idx;
      }
      int pool[3] = {0, 1, 2};                    // sample(range(0,3), 2)
      int j0 = (int)rng.randbelow(3); int c = pool[j0]; pool[j0] = pool[2];
      int j1 = (int)rng.randbelow(2); int t = pool[j1];
      int g = (int)rng.randbelow(10);             // choice(DOUBLE)
      gl.ty[idx] = 10 + g; gl.q0[idx] = c; gl.q1[idx] = t; gl.off[idx] = off;
      off += PC_D[g]; ++idx;
    }
  }
}

__device__ inline float2 cmul(float2 a, float2 b) {
  return make_float2(a.x * b.x - a.y * b.y, a.x * b.y + a.y * b.x);
}
__device__ inline float2 cadd(float2 a, float2 b) {
  return make_float2(a.x + b.x, a.y + b.y);
}
__device__ inline float2 shflx(float2 v, int m) {
  return make_float2(__shfl_xor(v.x, m), __shfl_xor(v.y, m));
}

// ---------------------------------------------------------------------------
// LDS layout (47104 B total, 2 blocks/CU):
//   [0, 40960)      g-staging: 512 rows x 40 halves (80 B stride, slots
//                   0..3 XOR-swizzled by (row>>3)&3; f0 at halves 32..35)
//     during build, the same region holds:
//       [0, 6144)       ldsU: U'[3][16][16] float2
//       [6144, 18432)   ldsA: A[12][16][16] float
//       [18432, 19072)  ldsP: staged params (<=160 floats)
//   [40960, 47104)  ldsT: T hi/lo mfma A-fragments, 3072 halves
// ---------------------------------------------------------------------------
__global__ __launch_bounds__(512, 4) void qconv_fused(
    const float* __restrict__ x, const float* __restrict__ params,
    float* __restrict__ out, GateList gl, int nP) {
  __shared__ __align__(16) char smem[47104];
  _Float16* ldsG = (_Float16*)smem;
  float2*   ldsU = (float2*)smem;
  float*    ldsA = (float*)(smem + 6144);
  float*    ldsP = (float*)(smem + 18432);
  _Float16* ldsT = (_Float16*)(smem + 40960);

  const int tid = threadIdx.x;
  const int bid = blockIdx.x;

  // ---- prologue: zero T fragments, stage params, prefetch both x tiles ----
  {
    uint64_t* z = (uint64_t*)ldsT;                // 6144 B = 768 u64
    for (int i = tid; i < 768; i += 512) z[i] = 0;
  }
  for (int i = tid; i < nP; i += 512) ldsP[i] = params[i];

  float2 plo[2], phi[2];
#pragma unroll
  for (int t2 = 0; t2 < 2; ++t2) {
    int r = bid * 1024 + t2 * 512 + tid;
    const float* xb = x + ((r >> 10) << 12) + (((r >> 5) & 31) << 7) + ((r & 31) << 1);
    plo[t2] = *(const float2*)(xb);               // qubit0=lo.x, 2=lo.y
    phi[t2] = *(const float2*)(xb + 64);          // qubit1=hi.x, 3=hi.y
  }
  __syncthreads();

  // ---- phase A: circuit evaluation (768 chains over 512 threads) ----
  // it=0: s=tid covers circ0 (waves 0-3) + circ1 (waves 4-7);
  // it=1: s=tid+512, tid<256 covers circ2 (waves 0-3).
#pragma unroll
  for (int it = 0; it < 2; ++it) {
    int s = tid + (it << 9);
    if (s < 768) {
      const int circ = __builtin_amdgcn_readfirstlane(s >> 8); // wave-uniform
      const int col  = (s >> 4) & 15;
      const int k    = s & 15;

      float2 st = make_float2(k == col ? 1.f : 0.f, 0.f);

      for (int g = 0; g < 15; ++g) {
        int gi = circ * 15 + g;
        int ty = gl.ty[gi];
        int o  = gl.off[gi];
        if (ty < 7) {
          float2 G00 = make_float2(1, 0), G01 = make_float2(0, 0),
                 G10 = make_float2(0, 0), G11 = make_float2(1, 0);
          if (ty == 0) {                 // rx
            float c, sn; __sincosf(ldsP[o] * 0.5f, &sn, &c);
            G00 = make_float2(c, 0); G01 = make_float2(0, -sn);
            G10 = make_float2(0, -sn); G11 = make_float2(c, 0);
          } else if (ty == 1) {          // ry
            float c, sn; __sincosf(ldsP[o] * 0.5f, &sn, &c);
            G00 = make_float2(c, 0); G01 = make_float2(-sn, 0);
            G10 = make_float2(sn, 0); G11 = make_float2(c, 0);
          } else if (ty == 2) {          // rz
            float c, sn; __sincosf(ldsP[o] * 0.5f, &sn, &c);
            G00 = make_float2(c, -sn); G11 = make_float2(c, sn);
          } else if (ty == 3) {          // s
            G11 = make_float2(0, 1);
          } else if (ty == 4) {          // t
            G11 = make_float2(0.7071067811865476f, 0.7071067811865476f);
          } else if (ty == 5) {          // p
            float cp, sp; __sincosf(ldsP[o], &sp, &cp);
            G11 = make_float2(cp, sp);
          } else {                       // u3
            float th = ldsP[o], phv = ldsP[o + 1], lm = ldsP[o + 2];
            float c, sn; __sincosf(th * 0.5f, &sn, &c);
            float cp, sp; __sincosf(phv, &sp, &cp);
            float cl, sl; __sincosf(lm, &sl, &cl);
            G00 = make_float2(c, 0);
            G01 = make_float2(-cl * sn, -sl * sn);
            G10 = make_float2(cp * sn, sp * sn);
            G11 = make_float2((cp * cl - sp * sl) * c, (cp * sl + sp * cl) * c);
          }
          int m = 1 << (3 - gl.q0[gi]);
          bool hib = (k & m) != 0;
          float2 p = shflx(st, m);
          float2 A = hib ? G11 : G00;
          float2 B = hib ? G10 : G01;
          st = cadd(cmul(A, st), cmul(B, p));
        } else {
          float2 G[4][4];
#pragma unroll
          for (int r2 = 0; r2 < 4; ++r2)
#pragma unroll
            for (int c2 = 0; c2 < 4; ++c2) G[r2][c2] = make_float2(0, 0);
          if (ty == 10) {                // rxx
            float c, sn; __sincosf(ldsP[o] * 0.5f, &sn, &c);
            G[0][0] = G[1][1] = G[2][2] = G[3][3] = make_float2(c, 0);
            G[0][3] = G[1][2] = G[2][1] = G[3][0] = make_float2(0, -sn);
          } else if (ty == 11) {         // ryy
            float c, sn; __sincosf(ldsP[o] * 0.5f, &sn, &c);
            G[0][0] = G[1][1] = G[2][2] = G[3][3] = make_float2(c, 0);
            G[0][3] = G[3][0] = make_float2(0, sn);
            G[1][2] = G[2][1] = make_float2(0, -sn);
          } else if (ty == 12) {         // rzz
            float c, sn; __sincosf(ldsP[o] * 0.5f, &sn, &c);
            G[0][0] = G[3][3] = make_float2(c, -sn);
            G[1][1] = G[2][2] = make_float2(c, sn);
          } else if (ty == 13) {         // swap
            G[0][0] = make_float2(1, 0); G[1][2] = make_float2(1, 0);
            G[2][1] = make_float2(1, 0); G[3][3] = make_float2(1, 0);
          } else if (ty == 14) {         // cnot
            G[0][0] = G[1][1] = make_float2(1, 0);
            G[2][3] = G[3][2] = make_float2(1, 0);
          } else if (ty == 15) {         // cp
            G[0][0] = G[1][1] = G[2][2] = make_float2(1, 0);
            float cp, sp; __sincosf(ldsP[o], &sp, &cp);
            G[3][3] = make_float2(cp, sp);
          } else if (ty == 16) {         // ch
            G[0][0] = G[1][1] = make_float2(1, 0);
            float rv = 0.7071067811865476f;
            G[2][2] = make_float2(rv, 0); G[2][3] = make_float2(rv, 0);
            G[3][2] = make_float2(rv, 0); G[3][3] = make_float2(-rv, 0);
          } else if (ty == 17) {         // cu
            G[0][0] = G[1][1] = make_float2(1, 0);
            float th = ldsP[o], phv = ldsP[o + 1], lm = ldsP[o + 2];
            float c, sn; __sincosf(th * 0.5f, &sn, &c);
            float cp, sp; __sincosf(phv, &sp, &cp);
            float cl, sl; __sincosf(lm, &sl, &cl);
            G[2][2] = make_float2(c, 0);
            G[2][3] = make_float2(-cl * sn, -sl * sn);
            G[3][2] = make_float2(cp * sn, sp * sn);
            G[3][3] = make_float2((cp * cl - sp * sl) * c, (cp * sl + sp * cl) * c);
          } else if (ty == 18) {         // ct
            G[0][0] = G[1][1] = G[2][2] = make_float2(1, 0);
            G[3][3] = make_float2(0.7071067811865476f, 0.7071067811865476f);
          } else {                       // cz
            G[0][0] = G[1][1] = G[2][2] = make_float2(1, 0);
            G[3][3] = make_float2(-1, 0);
          }
          int m0 = 1 << (3 - gl.q0[gi]);
          int m1 = 1 << (3 - gl.q1[gi]);
          bool b0 = (k & m0) != 0;
          bool b1 = (k & m1) != 0;
          float2 p0 = st;
          float2 p1 = shflx(st, m1);
          float2 p2 = shflx(st, m0);
          float2 p3 = shflx(st, m0 ^ m1);
          float2 acc = make_float2(0, 0);
#pragma unroll
          for (int jj = 0; jj < 4; ++jj) {
            float2 r0 = b1 ? G[1][1 ^ jj] : G[0][0 ^ jj];
            float2 r1 = b1 ? G[3][3 ^ jj] : G[2][2 ^ jj];
            float2 coef = b0 ? r1 : r0;
            float2 pj = (jj == 0) ? p0 : (jj == 1) ? p1 : (jj == 2) ? p2 : p3;
            acc = cadd(acc, cmul(coef, pj));
          }
          st = acc;
        }
      }

      int pc = __popc(col) & 3;
      float2 ph = make_float2(1, 0);
      if (pc == 1) ph = make_float2(0, -1);
      else if (pc == 2) ph = make_float2(-1, 0);
      else if (pc == 3) ph = make_float2(0, 1);
      float2 v = cmul(st, ph);

      ldsU[(circ * 16 + k) * 16 + col] = v;       // U'[row=k][col]
    }
  }
  __syncthreads();

  // ---- phase B: A_cq[k][l] with z-signs folded ----
#pragma unroll
  for (int it = 0; it < 2; ++it) {
    int s = tid + (it << 9);
    if (s < 768) {
      const int circ = s >> 8;
      const int k    = (s >> 4) & 15;
      const int l    = s & 15;
      float a0 = 0.f, a1 = 0.f, a2 = 0.f, a3 = 0.f;
#pragma unroll
      for (int i = 0; i < 16; ++i) {
        float2 uk = ldsU[(circ * 16 + i) * 16 + k];
        float2 ul = ldsU[(circ * 16 + i) * 16 + l];
        float t = uk.x * ul.x + uk.y * ul.y;
        a0 += (i & 8) ? -t : t;
        a1 += (i & 4) ? -t : t;
        a2 += (i & 2) ? -t : t;
        a3 += (i & 1) ? -t : t;
      }
      ldsA[((circ * 4 + 0) * 16 + k) * 16 + l] = a0;
      ldsA[((circ * 4 + 1) * 16 + k) * 16 + l] = a1;
      ldsA[((circ * 4 + 2) * 16 + k) * 16 + l] = a2;
      ldsA[((circ * 4 + 3) * 16 + k) * 16 + l] = a3;
    }
  }
  __syncthreads();

  // ---- phase C: T[cq][K] -> hi/lo f16 mfma A-fragments in ldsT ----
  for (int idx = tid; idx < 1152; idx += 512) {   // 12 channels x 96 K
    int cq = idx / 96;
    int K  = idx - cq * 96;
    int mf = K >> 5, r = K & 31;
    if (r >= 27) continue;                        // zero-padded
    int jarr[4] = {mf, r / 9, (r / 3) % 3, r % 3};
    float acc = 0.f;
    for (int sel = 0; sel < 16; ++sel) {
      int kk = 0, ll = 0;
      float sg = 1.f;
#pragma unroll
      for (int q = 0; q < 4; ++q) {
        int t = (sel >> (3 - q)) & 1;
        kk |= t << (3 - q);
        int lb = (jarr[q] == 2) ? (1 - t) : t;
        ll |= lb << (3 - q);
        if (jarr[q] == 1 && t) sg = -sg;
      }
      acc += sg * ldsA[(cq * 16 + kk) * 16 + ll];
    }
    float Tval = acc * 0.0625f;
    _Float16 th = (_Float16)Tval;
    _Float16 tl = (_Float16)(Tval - (float)th);
    int L  = ((r >> 3) << 4) | cq;
    int jj = r & 7;
    ldsT[((mf * 2 + 0) * 64 + L) * 8 + jj] = th;
    ldsT[((mf * 2 + 1) * 64 + L) * 8 + jj] = tl;
  }
  __syncthreads();

  // ---- main: per-wave 64 rows/tile, 2 tiles ----
  const int wid  = tid >> 6;
  const int lane = tid & 63;
  const int quad = lane >> 4;
  const int n16  = lane & 15;

  const half8* Tv = (const half8*)ldsT;
  half8 afh[3], afl[3];
#pragma unroll
  for (int mf = 0; mf < 3; ++mf) {
    afh[mf] = Tv[(mf * 2 + 0) * 64 + lane];
    afl[mf] = Tv[(mf * 2 + 1) * 64 + lane];
  }

#pragma unroll 1
  for (int t2 = 0; t2 < 2; ++t2) {
    // g123[27] = f1 (x) f2 (x) f3;  f0 = {1, c0, s0}
    float c0, s0, c1, s1, c2, s2, c3, s3;
    __sincosf(plo[t2].x, &s0, &c0);
    __sincosf(phi[t2].x, &s1, &c1);
    __sincosf(plo[t2].y, &s2, &c2);
    __sincosf(phi[t2].y, &s3, &c3);

    float f1a[3] = {1.f, c1, s1};
    float f23[9];
    {
      float f2a[3] = {1.f, c2, s2}, f3a[3] = {1.f, c3, s3};
#pragma unroll
      for (int a = 0; a < 9; ++a) f23[a] = f2a[a / 3] * f3a[a % 3];
    }
    __align__(16) _Float16 gh[32];
#pragma unroll
    for (int r1 = 0; r1 < 3; ++r1)
#pragma unroll
      for (int b9 = 0; b9 < 9; ++b9)
        gh[r1 * 9 + b9] = (_Float16)(f1a[r1] * f23[b9]);
#pragma unroll
    for (int e = 27; e < 32; ++e) gh[e] = (_Float16)0.f;

    {
      // slot-swizzled write: memory slot s holds content s^wkey, wkey=(row>>3)&3.
      // Breaks the 8-way ds_write_b128 bank conflict of the 80 B row stride.
      half8* dst = (half8*)&ldsG[tid * 40];
      int wkey = (tid >> 3) & 3;
      dst[0 ^ wkey] = *(const half8*)&gh[0];
      dst[1 ^ wkey] = *(const half8*)&gh[8];
      dst[2 ^ wkey] = *(const half8*)&gh[16];
      dst[3 ^ wkey] = *(const half8*)&gh[24];
      half4 f0h = {(_Float16)1.f, (_Float16)c0, (_Float16)s0, (_Float16)0.f};
      *(half4*)&ldsG[tid * 40 + 32] = f0h;
    }
    __syncthreads();

    // per 16-row set t: slice quad*8..+8 (swizzled slot) + f0 triple
    half8 slice[4];
    half4 f0v[4];
#pragma unroll
    for (int t = 0; t < 4; ++t) {
      const int row = wid * 64 + t * 16 + n16;
      const int rkey = (row >> 3) & 3;
      slice[t] = *(const half8*)&ldsG[row * 40 + ((quad ^ rkey) << 3)];
      f0v[t]   = *(const half4*)&ldsG[row * 40 + 32];
    }

    float4v acc[4];
#pragma unroll
    for (int t = 0; t < 4; ++t) acc[t] = (float4v){0.f, 0.f, 0.f, 0.f};
#pragma unroll
    for (int mf = 0; mf < 3; ++mf) {
#pragma unroll
      for (int t = 0; t < 4; ++t) {
        _Float16 f0s = f0v[t][mf];
        half8 bf;
#pragma unroll
        for (int e = 0; e < 8; ++e) bf[e] = slice[t][e] * f0s;
        acc[t] = __builtin_amdgcn_mfma_f32_16x16x32_f16(afl[mf], bf, acc[t], 0, 0, 0);
        acc[t] = __builtin_amdgcn_mfma_f32_16x16x32_f16(afh[mf], bf, acc[t], 0, 0, 0);
      }
    }

    // C layout: col = n16 = data row, row = quad*4+v = channel (12 used)
    if (quad < 3) {
#pragma unroll
      for (int t = 0; t < 4; ++t) {
        int rowg = bid * 1024 + t2 * 512 + wid * 64 + t * 16 + n16;
        float4v ev = acc[t];
        __builtin_nontemporal_store(ev, (float4v*)(out + (size_t)rowg * 12 + quad * 4));
      }
    }
    if (t2 == 0) __syncthreads();   // protect ldsG before tile-1 overwrite
  }
}

}  // namespace

extern "C" void kernel_launch(void* const* d_in, const int* in_sizes, int n_in,
                              void* d_out, int out_size, void* d_ws, size_t ws_size,
                              hipStream_t stream) {
  const float* x      = (const float*)d_in[0];
  const float* params = (const float*)d_in[1];
  float* out = (float*)d_out;
  (void)d_ws; (void)ws_size;       // workspace unused — T lives in LDS now

  GateList gl;
  build_gatelist(gl);              // deterministic every call (seed 1024)

  int nP = in_sizes[1];            // param element count
  if (nP > 160) nP = 160;          // ldsP capacity guard

  int nrows = in_sizes[0] / 4;     // 524288
  int grid  = nrows / 1024;        // 512 blocks x 512 threads x 2 tiles
  hipLaunchKernelGGL(qconv_fused, dim3(grid), dim3(512), 0, stream,
                     x, params, out, gl, nP);
}

// Round 2
// 81.433 us; speedup vs baseline: 1.0629x; 1.0629x over previous
//
#include <hip/hip_runtime.h>
#include <stdint.h>

// ---------------------------------------------------------------------------
// RandomParameterizedQuantumConvolutionLayer — linear form out = T(12x81)·G.
// g factorizes: g[K] = f0[mf] * g123[r], K = mf*32+r (r<27 used), with
// f0 = {1, cos a0, sin a0}, g123 = f1 (x) f2 (x) f3. Rows stage only
// g123[32h] + f0[4h] (72 B) in LDS; consumer rebuilds B-fragments with 4
// packed f16 muls per (t,mf). build_T: register+shfl circuit eval -> A_cq ->
// per-qubit contraction -> T hi/lo f16 A-fragments in d_ws.
// Round-2: split structure restored (fused variant regressed);
//   + LDS param staging in build_T (parallel param fetch, LDS-hit chain)
//   + XOR slot swizzle on g-staging (kills 8-way ds_write_b128 conflict)
//   + early-issue T-fragment loads in qconv_main (hide under sincos phase)
// ---------------------------------------------------------------------------

namespace {

typedef _Float16 half8 __attribute__((ext_vector_type(8)));
typedef _Float16 half4 __attribute__((ext_vector_type(4)));
typedef float float4v __attribute__((ext_vector_type(4)));

struct GateList {
  int ty[45];   // 0..6 single (rx,ry,rz,s,t,p,u3); 10..19 double
  int q0[45];
  int q1[45];
  int off[45];  // param offset
};

// ---- CPython-compatible MT19937 (random.Random) ----
struct PyRandom {
  uint32_t mt[624];
  int mti;
  void init_genrand(uint32_t s) {
    mt[0] = s;
    for (int i = 1; i < 624; ++i)
      mt[i] = 1812433253u * (mt[i - 1] ^ (mt[i - 1] >> 30)) + (uint32_t)i;
    mti = 624;
  }
  void init_by_array(const uint32_t* key, int klen) {
    init_genrand(19650218u);
    int i = 1, j = 0;
    int k = 624 > klen ? 624 : klen;
    for (; k; --k) {
      mt[i] = (mt[i] ^ ((mt[i - 1] ^ (mt[i - 1] >> 30)) * 1664525u)) + key[j] + (uint32_t)j;
      ++i; ++j;
      if (i >= 624) { mt[0] = mt[623]; i = 1; }
      if (j >= klen) j = 0;
    }
    for (k = 623; k; --k) {
      mt[i] = (mt[i] ^ ((mt[i - 1] ^ (mt[i - 1] >> 30)) * 1566083941u)) - (uint32_t)i;
      ++i;
      if (i >= 624) { mt[0] = mt[623]; i = 1; }
    }
    mt[0] = 0x80000000u;
    mti = 624;
  }
  uint32_t genrand() {
    if (mti >= 624) {
      const uint32_t mag[2] = {0u, 0x9908b0dfu};
      int kk; uint32_t y;
      for (kk = 0; kk < 227; ++kk) {
        y = (mt[kk] & 0x80000000u) | (mt[kk + 1] & 0x7fffffffu);
        mt[kk] = mt[kk + 397] ^ (y >> 1) ^ mag[y & 1];
      }
      for (; kk < 623; ++kk) {
        y = (mt[kk] & 0x80000000u) | (mt[kk + 1] & 0x7fffffffu);
        mt[kk] = mt[kk - 227] ^ (y >> 1) ^ mag[y & 1];
      }
      y = (mt[623] & 0x80000000u) | (mt[0] & 0x7fffffffu);
      mt[623] = mt[396] ^ (y >> 1) ^ mag[y & 1];
      mti = 0;
    }
    uint32_t y = mt[mti++];
    y ^= y >> 11;
    y ^= (y << 7) & 0x9d2c5680u;
    y ^= (y << 15) & 0xefc60000u;
    y ^= y >> 18;
    return y;
  }
  uint32_t getrandbits(int k) { return genrand() >> (32 - k); }
  uint32_t randbelow(uint32_t n) {
    int k = 32 - __builtin_clz(n);
    uint32_t r = getrandbits(k);
    while (r >= n) r = getrandbits(k);
    return r;
  }
};

void build_gatelist(GateList& gl) {
  PyRandom rng;
  uint32_t key = 1024u;
  rng.init_by_array(&key, 1);
  static const int PC_S[7]  = {1, 1, 1, 0, 0, 1, 3};
  static const int PC_D[10] = {1, 1, 1, 0, 0, 1, 0, 3, 0, 0};
  int off = 0, idx = 0;
  for (int circ = 0; circ < 3; ++circ) {
    for (int blk = 0; blk < 3; ++blk) {
      for (int i = 0; i < 4; ++i) {
        int g = (int)rng.randbelow(7);            // choice(SINGLE)
        gl.ty[idx] = g; gl.q0[idx] = i; gl.q1[idx] = 0; gl.off[idx] = off;
        off += PC_S[g]; ++idx;
      }
      int pool[3] = {0, 1, 2};                    // sample(range(0,3), 2)
      int j0 = (int)rng.randbelow(3); int c = pool[j0]; pool[j0] = pool[2];
      int j1 = (int)rng.randbelow(2); int t = pool[j1];
      int g = (int)rng.randbelow(10);             // choice(DOUBLE)
      gl.ty[idx] = 10 + g; gl.q0[idx] = c; gl.q1[idx] = t; gl.off[idx] = off;
      off += PC_D[g]; ++idx;
    }
  }
}

__device__ inline float2 cmul(float2 a, float2 b) {
  return make_float2(a.x * b.x - a.y * b.y, a.x * b.y + a.y * b.x);
}
__device__ inline float2 cadd(float2 a, float2 b) {
  return make_float2(a.x + b.x, a.y + b.y);
}
__device__ inline float2 shflx(float2 v, int m) {
  return make_float2(__shfl_xor(v.x, m), __shfl_xor(v.y, m));
}

// ---------------------------------------------------------------------------
// build_T: one 768-thread block.
// Phase 0: stage params into LDS (parallel fetch; the 15-gate serial chain
//   then hits LDS instead of serialized cache accesses).
// Phase A: tid = circ*256 + col*16 + k -> U'[row=k][col] in register.
// Phase B: A_cq[k][l] = sum_i sign_q(i) Re(U'[i,k] conj(U'[i,l])).
// Phase C: T[cq][K], K = mf*32 + r, feature = f_{q0}[mf]*f_{q1}[r/9]*
//   f_{q2}[(r/3)%3]*f_{q3}[r%3] (f = {1,cos,sin}); r>=27 stays zero.
//   Split hi/lo f16; store as mfma A-fragments: lane L=(r>>3)*16+cq, slot r&7.
// ---------------------------------------------------------------------------
__global__ __launch_bounds__(768) void build_T(
    const float* __restrict__ params, _Float16* __restrict__ Tws, GateList gl,
    int nP) {
  __shared__ float2 ldsU[768];    // U'[c][row][col] at (c*16+row)*16+col
  __shared__ float  ldsA[3072];   // A[cq][k][l] at ((cq)*16+k)*16+l
  __shared__ float  ldsP[160];    // staged params

  const int tid = threadIdx.x;

  // zero the fragment region (d_ws is poisoned 0xAA every launch)
  ((uint64_t*)Tws)[tid] = 0ull;   // 768 * 8B = 3072 halves

  if (tid < nP) ldsP[tid] = params[tid];
  __syncthreads();

  // ---- phase A: circuit evaluation ----
  {
    const int circ = tid >> 8;
    const int col  = (tid >> 4) & 15;
    const int k    = tid & 15;

    float2 s = make_float2(k == col ? 1.f : 0.f, 0.f);

    for (int g = 0; g < 15; ++g) {
      int gi = circ * 15 + g;
      int ty = gl.ty[gi];
      int o  = gl.off[gi];
      if (ty < 7) {
        float2 G00 = make_float2(1, 0), G01 = make_float2(0, 0),
               G10 = make_float2(0, 0), G11 = make_float2(1, 0);
        if (ty == 0) {                 // rx
          float c, sn; __sincosf(ldsP[o] * 0.5f, &sn, &c);
          G00 = make_float2(c, 0); G01 = make_float2(0, -sn);
          G10 = make_float2(0, -sn); G11 = make_float2(c, 0);
        } else if (ty == 1) {          // ry
          float c, sn; __sincosf(ldsP[o] * 0.5f, &sn, &c);
          G00 = make_float2(c, 0); G01 = make_float2(-sn, 0);
          G10 = make_float2(sn, 0); G11 = make_float2(c, 0);
        } else if (ty == 2) {          // rz
          float c, sn; __sincosf(ldsP[o] * 0.5f, &sn, &c);
          G00 = make_float2(c, -sn); G11 = make_float2(c, sn);
        } else if (ty == 3) {          // s
          G11 = make_float2(0, 1);
        } else if (ty == 4) {          // t
          G11 = make_float2(0.7071067811865476f, 0.7071067811865476f);
        } else if (ty == 5) {          // p
          float cp, sp; __sincosf(ldsP[o], &sp, &cp);
          G11 = make_float2(cp, sp);
        } else {                       // u3
          float th = ldsP[o], phv = ldsP[o + 1], lm = ldsP[o + 2];
          float c, sn; __sincosf(th * 0.5f, &sn, &c);
          float cp, sp; __sincosf(phv, &sp, &cp);
          float cl, sl; __sincosf(lm, &sl, &cl);
          G00 = make_float2(c, 0);
          G01 = make_float2(-cl * sn, -sl * sn);
          G10 = make_float2(cp * sn, sp * sn);
          G11 = make_float2((cp * cl - sp * sl) * c, (cp * sl + sp * cl) * c);
        }
        int m = 1 << (3 - gl.q0[gi]);
        bool hib = (k & m) != 0;
        float2 p = shflx(s, m);
        float2 A = hib ? G11 : G00;
        float2 B = hib ? G10 : G01;
        s = cadd(cmul(A, s), cmul(B, p));
      } else {
        float2 G[4][4];
#pragma unroll
        for (int r2 = 0; r2 < 4; ++r2)
#pragma unroll
          for (int c2 = 0; c2 < 4; ++c2) G[r2][c2] = make_float2(0, 0);
        if (ty == 10) {                // rxx
          float c, sn; __sincosf(ldsP[o] * 0.5f, &sn, &c);
          G[0][0] = G[1][1] = G[2][2] = G[3][3] = make_float2(c, 0);
          G[0][3] = G[1][2] = G[2][1] = G[3][0] = make_float2(0, -sn);
        } else if (ty == 11) {         // ryy
          float c, sn; __sincosf(ldsP[o] * 0.5f, &sn, &c);
          G[0][0] = G[1][1] = G[2][2] = G[3][3] = make_float2(c, 0);
          G[0][3] = G[3][0] = make_float2(0, sn);
          G[1][2] = G[2][1] = make_float2(0, -sn);
        } else if (ty == 12) {         // rzz
          float c, sn; __sincosf(ldsP[o] * 0.5f, &sn, &c);
          G[0][0] = G[3][3] = make_float2(c, -sn);
          G[1][1] = G[2][2] = make_float2(c, sn);
        } else if (ty == 13) {         // swap
          G[0][0] = make_float2(1, 0); G[1][2] = make_float2(1, 0);
          G[2][1] = make_float2(1, 0); G[3][3] = make_float2(1, 0);
        } else if (ty == 14) {         // cnot
          G[0][0] = G[1][1] = make_float2(1, 0);
          G[2][3] = G[3][2] = make_float2(1, 0);
        } else if (ty == 15) {         // cp
          G[0][0] = G[1][1] = G[2][2] = make_float2(1, 0);
          float cp, sp; __sincosf(ldsP[o], &sp, &cp);
          G[3][3] = make_float2(cp, sp);
        } else if (ty == 16) {         // ch
          G[0][0] = G[1][1] = make_float2(1, 0);
          float rv = 0.7071067811865476f;
          G[2][2] = make_float2(rv, 0); G[2][3] = make_float2(rv, 0);
          G[3][2] = make_float2(rv, 0); G[3][3] = make_float2(-rv, 0);
        } else if (ty == 17) {         // cu
          G[0][0] = G[1][1] = make_float2(1, 0);
          float th = ldsP[o], phv = ldsP[o + 1], lm = ldsP[o + 2];
          float c, sn; __sincosf(th * 0.5f, &sn, &c);
          float cp, sp; __sincosf(phv, &sp, &cp);
          float cl, sl; __sincosf(lm, &sl, &cl);
          G[2][2] = make_float2(c, 0);
          G[2][3] = make_float2(-cl * sn, -sl * sn);
          G[3][2] = make_float2(cp * sn, sp * sn);
          G[3][3] = make_float2((cp * cl - sp * sl) * c, (cp * sl + sp * cl) * c);
        } else if (ty == 18) {         // ct
          G[0][0] = G[1][1] = G[2][2] = make_float2(1, 0);
          G[3][3] = make_float2(0.7071067811865476f, 0.7071067811865476f);
        } else {                       // cz
          G[0][0] = G[1][1] = G[2][2] = make_float2(1, 0);
          G[3][3] = make_float2(-1, 0);
        }
        int m0 = 1 << (3 - gl.q0[gi]);
        int m1 = 1 << (3 - gl.q1[gi]);
        bool b0 = (k & m0) != 0;
        bool b1 = (k & m1) != 0;
        float2 p0 = s;
        float2 p1 = shflx(s, m1);
        float2 p2 = shflx(s, m0);
        float2 p3 = shflx(s, m0 ^ m1);
        float2 acc = make_float2(0, 0);
#pragma unroll
        for (int jj = 0; jj < 4; ++jj) {
          float2 r0 = b1 ? G[1][1 ^ jj] : G[0][0 ^ jj];
          float2 r1 = b1 ? G[3][3 ^ jj] : G[2][2 ^ jj];
          float2 coef = b0 ? r1 : r0;
          float2 pj = (jj == 0) ? p0 : (jj == 1) ? p1 : (jj == 2) ? p2 : p3;
          acc = cadd(acc, cmul(coef, pj));
        }
        s = acc;
      }
    }

    int pc = __popc(col) & 3;
    float2 ph = make_float2(1, 0);
    if (pc == 1) ph = make_float2(0, -1);
    else if (pc == 2) ph = make_float2(-1, 0);
    else if (pc == 3) ph = make_float2(0, 1);
    float2 v = cmul(s, ph);

    ldsU[(circ * 16 + k) * 16 + col] = v;   // U'[row=k][col]
  }
  __syncthreads();

  // ---- phase B ----
  {
    const int circ = tid >> 8;
    const int k    = (tid >> 4) & 15;
    const int l    = tid & 15;
    float a0 = 0.f, a1 = 0.f, a2 = 0.f, a3 = 0.f;
#pragma unroll
    for (int i = 0; i < 16; ++i) {
      float2 uk = ldsU[(circ * 16 + i) * 16 + k];
      float2 ul = ldsU[(circ * 16 + i) * 16 + l];
      float t = uk.x * ul.x + uk.y * ul.y;
      a0 += (i & 8) ? -t : t;
      a1 += (i & 4) ? -t : t;
      a2 += (i & 2) ? -t : t;
      a3 += (i & 1) ? -t : t;
    }
    ldsA[((circ * 4 + 0) * 16 + k) * 16 + l] = a0;
    ldsA[((circ * 4 + 1) * 16 + k) * 16 + l] = a1;
    ldsA[((circ * 4 + 2) * 16 + k) * 16 + l] = a2;
    ldsA[((circ * 4 + 3) * 16 + k) * 16 + l] = a3;
  }
  __syncthreads();

  // ---- phase C: K = mf*32 + r; feature jarr = {mf, r/9, (r/3)%3, r%3} ----
  for (int idx = tid; idx < 1152; idx += 768) {   // 12 channels x 96 K
    int cq = idx / 96;
    int K  = idx - cq * 96;
    int mf = K >> 5, r = K & 31;
    if (r >= 27) continue;                        // zero-padded
    int jarr[4] = {mf, r / 9, (r / 3) % 3, r % 3};
    float acc = 0.f;
    for (int sel = 0; sel < 16; ++sel) {
      int kk = 0, ll = 0;
      float sg = 1.f;
#pragma unroll
      for (int q = 0; q < 4; ++q) {
        int t = (sel >> (3 - q)) & 1;
        kk |= t << (3 - q);
        int lb = (jarr[q] == 2) ? (1 - t) : t;
        ll |= lb << (3 - q);
        if (jarr[q] == 1 && t) sg = -sg;
      }
      acc += sg * ldsA[(cq * 16 + kk) * 16 + ll];
    }
    float T = acc * 0.0625f;
    _Float16 th = (_Float16)T;
    _Float16 tl = (_Float16)(T - (float)th);
    int L  = ((r >> 3) << 4) | cq;
    int jj = r & 7;
    Tws[((mf * 2 + 0) * 64 + L) * 8 + jj] = th;
    Tws[((mf * 2 + 1) * 64 + L) * 8 + jj] = tl;
  }
}

// ---------------------------------------------------------------------------
// qconv_main: block = 256 threads (4 waves, 256 rows), grid 2048.
// Per lane: 2x2 patch -> 4 sincos -> g123[27] (f1 (x) f2 (x) f3) + f0 triple
// -> f16 -> LDS (row stride 40 halves = 80 B; 16B slots 0..3 XOR-swizzled by
// (row>>3)&3 to break the 8-way ds_write_b128 bank conflict; 20 KB/block ->
// 4 blocks/CU). T-fragment loads issued early (latency hidden under sincos
// phase). Per 16-row set t: 1 ds_read_b128 (swizzled slot) + 1 ds_read_b64
// (f0, broadcast) -> bf = f0[mf]*slice (packed f16) -> 6 chained
// mfma_f32_16x16x32_f16 over (mf, hi/lo); 4 independent acc chains; direct
// C-layout nontemporal float4 store.
// ---------------------------------------------------------------------------
__global__ __launch_bounds__(256, 4) void qconv_main(
    const float* __restrict__ x, const _Float16* __restrict__ T,
    float* __restrict__ out) {
  __shared__ _Float16 lds[256 * 40];
  const int tid  = threadIdx.x;
  const int wid  = tid >> 6;
  const int lane = tid & 63;
  const int quad = lane >> 4;
  const int n16  = lane & 15;
  const int r = blockIdx.x * 256 + tid;

  // 2x2 patch -> 4 angles (qubit0=lo.x, 1=hi.x, 2=lo.y, 3=hi.y)
  const int b  = r >> 10;
  const int h2 = (r >> 5) & 31;
  const int j  = r & 31;
  const float* xb = x + b * 4096 + h2 * 128 + j * 2;
  float2 lo = *(const float2*)(xb);
  float2 hi = *(const float2*)(xb + 64);

  // A-fragments (T hi/lo per K-chunk) — issue early, consume after sync
  const half8* Tv = (const half8*)T;
  half8 afh[3], afl[3];
#pragma unroll
  for (int mf = 0; mf < 3; ++mf) {
    afh[mf] = Tv[(mf * 2 + 0) * 64 + lane];
    afl[mf] = Tv[(mf * 2 + 1) * 64 + lane];
  }

  float c0, s0, c1, s1, c2, s2, c3, s3;
  __sincosf(lo.x, &s0, &c0);
  __sincosf(hi.x, &s1, &c1);
  __sincosf(lo.y, &s2, &c2);
  __sincosf(hi.y, &s3, &c3);

  // g123[27] = f1 (x) f2 (x) f3;  f0 = {1, c0, s0}
  float f1a[3] = {1.f, c1, s1};
  float f23[9];
  {
    float f2a[3] = {1.f, c2, s2}, f3a[3] = {1.f, c3, s3};
#pragma unroll
    for (int a = 0; a < 9; ++a) f23[a] = f2a[a / 3] * f3a[a % 3];
  }
  __align__(16) _Float16 gh[32];
#pragma unroll
  for (int r1 = 0; r1 < 3; ++r1)
#pragma unroll
    for (int b9 = 0; b9 < 9; ++b9)
      gh[r1 * 9 + b9] = (_Float16)(f1a[r1] * f23[b9]);
#pragma unroll
  for (int e = 27; e < 32; ++e) gh[e] = (_Float16)0.f;

  {
    // slot-swizzled write: memory slot s holds content s^wkey, wkey=(row>>3)&3.
    // Breaks the 8-way ds_write_b128 bank conflict of the 80 B row stride.
    half8* dst = (half8*)&lds[tid * 40];
    int wkey = (tid >> 3) & 3;
    dst[0 ^ wkey] = *(const half8*)&gh[0];
    dst[1 ^ wkey] = *(const half8*)&gh[8];
    dst[2 ^ wkey] = *(const half8*)&gh[16];
    dst[3 ^ wkey] = *(const half8*)&gh[24];
    half4 f0h = {(_Float16)1.f, (_Float16)c0, (_Float16)s0, (_Float16)0.f};
    *(half4*)&lds[tid * 40 + 32] = f0h;
  }
  __syncthreads();

  // load all 4 sets' slices (swizzled slot) + f0 triples (wave-local rows)
  half8 slice[4];
  half4 f0v[4];
#pragma unroll
  for (int t = 0; t < 4; ++t) {
    const int row = wid * 64 + t * 16 + n16;
    const int rkey = (row >> 3) & 3;
    slice[t] = *(const half8*)&lds[row * 40 + ((quad ^ rkey) << 3)];
    f0v[t]   = *(const half4*)&lds[row * 40 + 32];
  }

  float4v acc[4];
#pragma unroll
  for (int t = 0; t < 4; ++t) acc[t] = (float4v){0.f, 0.f, 0.f, 0.f};
#pragma unroll
  for (int mf = 0; mf < 3; ++mf) {
#pragma unroll
    for (int t = 0; t < 4; ++t) {
      _Float16 f0s = f0v[t][mf];
      half8 bf;
#pragma unroll
      for (int e = 0; e < 8; ++e) bf[e] = slice[t][e] * f0s;
      acc[t] = __builtin_amdgcn_mfma_f32_16x16x32_f16(afl[mf], bf, acc[t], 0, 0, 0);
      acc[t] = __builtin_amdgcn_mfma_f32_16x16x32_f16(afh[mf], bf, acc[t], 0, 0, 0);
    }
  }

  // C layout: col = n16 = data row, row = quad*4+v = channel (12 used)
  if (quad < 3) {
#pragma unroll
    for (int t = 0; t < 4; ++t) {
      int rowg = blockIdx.x * 256 + wid * 64 + t * 16 + n16;
      float4v ev = acc[t];
      __builtin_nontemporal_store(ev, (float4v*)(out + (size_t)rowg * 12 + quad * 4));
    }
  }
}

}  // namespace

extern "C" void kernel_launch(void* const* d_in, const int* in_sizes, int n_in,
                              void* d_out, int out_size, void* d_ws, size_t ws_size,
                              hipStream_t stream) {
  const float* x      = (const float*)d_in[0];
  const float* params = (const float*)d_in[1];
  float* out = (float*)d_out;
  _Float16* Tws = (_Float16*)d_ws;   // 3072 halves (6 KB) used

  GateList gl;
  build_gatelist(gl);                // deterministic every call (seed 1024)

  int nP = in_sizes[1];              // param element count
  if (nP > 160) nP = 160;            // ldsP capacity guard

  hipLaunchKernelGGL(build_T, dim3(1), dim3(768), 0, stream, params, Tws, gl, nP);

  int nrows = in_sizes[0] / 4;       // 524288
  int grid  = nrows / 256;           // 2048 blocks
  hipLaunchKernelGGL(qconv_main, dim3(grid), dim3(256), 0, stream,
                     x, Tws, out);
}